// Round 4
// baseline (329.697 us; speedup 1.0000x reference)
//
#include <hip/hip_runtime.h>
#include <hip/hip_bf16.h>

#define NN 8192
#define ND 128
#define BSZ 4096
#define CTX1 32
#define SRC 4096
#define TOPK 8
#define DROPC 5

using f4 = __attribute__((ext_vector_type(4))) float;
using bfrag = __attribute__((ext_vector_type(8))) short;

__device__ __forceinline__ short f2bf(float x) {
  __hip_bfloat16 h = __float2bfloat16(x);
  return __builtin_bit_cast(short, h);
}

typedef const __attribute__((address_space(1))) char* gas1_t;
typedef __attribute__((address_space(3))) char* las3_t;
// async global->LDS, 16B per lane; LDS dest = wave-uniform base + lane*16
__device__ __forceinline__ void gll16(const void* g, void* l) {
  __builtin_amdgcn_global_load_lds((gas1_t)(uintptr_t)g,
                                   (las3_t)(uint32_t)(uintptr_t)l, 16, 0, 0);
}

// ---------------- prep: tfn (normalized trainfeature[:, :64]), wsum, meanpara ----
__global__ __launch_bounds__(256) void prep_kernel(
    const float* __restrict__ trainfeature, const float* __restrict__ bsnf,
    const float* __restrict__ para, float* __restrict__ tfn,
    float* __restrict__ wsum, float* __restrict__ meanpara) {
  int blk = blockIdx.x;
  int t = threadIdx.x;
  if (blk < 2048) {                      // tfn: 4 rows per block, one wave per row
    int row = blk * 4 + (t >> 6);
    int j = t & 63;
    float x = trainfeature[(size_t)row * ND + j];
    float ss = x * x;
    #pragma unroll
    for (int o = 32; o > 0; o >>= 1) ss += __shfl_xor(ss, o);
    float nrm = sqrtf(ss) + 1e-8f;
    tfn[(size_t)row * 64 + j] = x / nrm;
  } else if (blk < 4096) {               // wsum: 2 rows per block
    int b = (blk - 2048) * 2 + (t >> 7);
    int k = t & 127;
    float s = 0.f;
    #pragma unroll
    for (int tt = 0; tt < TOPK; ++tt)
      s += para[tt] * bsnf[((size_t)b * TOPK + tt) * ND + k];
    wsum[(size_t)b * ND + k] = s * (1.0f / TOPK);
  } else {
    if (t == 0) {
      float s = 0.f;
      for (int tt = 0; tt < TOPK; ++tt) s += para[tt];
      *meanpara = s * (1.0f / TOPK);
    }
  }
}

// ---------------- generic f32 GEMM body: C[M][128] = A[M][128] @ W[128][128]
// Optional f32 output Cf. Optional bf16 MFMA-fragment-packed output Xpack:
// frag (kt,nt) is 64 lanes x 8 shorts contiguous (1KB); lane l, elem j holds
// X[kt*32 + (l>>4)*8 + j][nt*16 + (l&15)].
__device__ __forceinline__ void gemm128_body(
    const float* __restrict__ A, const float* __restrict__ W,
    const float* __restrict__ bias, const float* __restrict__ bscale_ptr,
    float* __restrict__ Cf, short* __restrict__ Xpack, int row0) {
  __shared__ float Ws[128][132];
  __shared__ float As[64][128];
  int t = threadIdx.x;
  for (int i = t; i < 128 * 32; i += 256) {
    int r = i >> 5, c = (i & 31) * 4;
    *(f4*)&Ws[r][c] = *(const f4*)&W[(size_t)r * 128 + c];
  }
  for (int i = t; i < 64 * 32; i += 256) {
    int r = i >> 5, c = (i & 31) * 4;
    *(f4*)&As[r][c] = *(const f4*)&A[(size_t)(row0 + r) * 128 + c];
  }
  __syncthreads();
  int tr = (t >> 5) * 8;
  int tc = (t & 31) * 4;
  float acc[8][4];
  #pragma unroll
  for (int i = 0; i < 8; i++)
    #pragma unroll
    for (int j = 0; j < 4; j++) acc[i][j] = 0.f;
  for (int k = 0; k < 128; k++) {
    f4 w = *(const f4*)&Ws[k][tc];
    #pragma unroll
    for (int i = 0; i < 8; i++) {
      float a = As[tr + i][k];
      acc[i][0] = fmaf(a, w[0], acc[i][0]);
      acc[i][1] = fmaf(a, w[1], acc[i][1]);
      acc[i][2] = fmaf(a, w[2], acc[i][2]);
      acc[i][3] = fmaf(a, w[3], acc[i][3]);
    }
  }
  if (bias) {
    float bsc = bscale_ptr ? *bscale_ptr : 1.0f;
    #pragma unroll
    for (int i = 0; i < 8; i++)
      #pragma unroll
      for (int j = 0; j < 4; j++) acc[i][j] += bias[tc + j] * bsc;
  }
  if (Cf) {
    #pragma unroll
    for (int i = 0; i < 8; i++) {
      int r = row0 + tr + i;
      #pragma unroll
      for (int j = 0; j < 4; j++) Cf[(size_t)r * 128 + tc + j] = acc[i][j];
    }
  }
  if (Xpack) {
    int kb = row0 + tr;              // multiple of 8
    int kt = kb >> 5;
    int lane_hi = (kb >> 3) & 3;
    #pragma unroll
    for (int j = 0; j < 4; j++) {
      int n = tc + j;
      int ln = (n & 15) | (lane_hi << 4);
      bfrag h;
      #pragma unroll
      for (int i = 0; i < 8; i++) h[i] = f2bf(acc[i][j]);
      *(bfrag*)&Xpack[((size_t)(kt * 8 + (n >> 4)) * 64 + ln) * 8] = h;
    }
  }
}

__global__ __launch_bounds__(256) void gemm128_kernel(
    const float* __restrict__ A, const float* __restrict__ W,
    const float* __restrict__ bias, const float* __restrict__ bscale_ptr,
    float* __restrict__ Cf, short* __restrict__ Xpack) {
  gemm128_body(A, W, bias, bscale_ptr, Cf, Xpack, blockIdx.x * 64);
}

// 2 projections in one launch, writing MFMA-packed bf16
__global__ __launch_bounds__(256) void proj2_kernel(
    const float* __restrict__ A0, const float* __restrict__ W0, short* __restrict__ T0,
    const float* __restrict__ A1, const float* __restrict__ W1, short* __restrict__ T1) {
  if (blockIdx.y == 0)
    gemm128_body(A0, W0, nullptr, nullptr, nullptr, T0, blockIdx.x * 64);
  else
    gemm128_body(A1, W1, nullptr, nullptr, nullptr, T1, blockIdx.x * 64);
}

// QKV in one launch
__global__ __launch_bounds__(256) void qkv_kernel(
    const float* __restrict__ A, const float* __restrict__ Wq,
    const float* __restrict__ Wk, const float* __restrict__ Wv,
    float* __restrict__ Qa, float* __restrict__ Ka, float* __restrict__ Va) {
  const float* W = blockIdx.y == 0 ? Wq : (blockIdx.y == 1 ? Wk : Wv);
  float* C = blockIdx.y == 0 ? Qa : (blockIdx.y == 1 ? Ka : Va);
  gemm128_body(A, W, nullptr, nullptr, C, nullptr, blockIdx.x * 64);
}

// ---------------- big GEMM: partial[g][split] = A_f32(8192x8192) @ X_bf16(8192x128)
// m97/T3-T4 structure: global_load_lds staging into double-buffered LDS,
// raw s_barrier + counted vmcnt(6) (never drained to 0 in the main loop).
// A f32 tile swizzled both-sides (pre-swizzled global source + swizzled read):
// LDS float idx(row,u) = row*32 + (u ^ (row&7))*4  for 16B unit u in 0..7.
__global__ __launch_bounds__(256, 3) void big_gemm_kernel(
    const float* __restrict__ adj, const float* __restrict__ graphm,
    const short* __restrict__ XgP, const short* __restrict__ XEP,
    float* __restrict__ partials, int ksplit, int kc) {
  const int g = blockIdx.z;
  const float* __restrict__ Am = g ? graphm : adj;
  const short* __restrict__ Xp = g ? XEP : XgP;
  const int m0 = blockIdx.x * 128;
  const int t = threadIdx.x;
  const int lane = t & 63;
  const int w = t >> 6;

  __shared__ float Asw[2][4096];   // 2 x 16 KB : 128 rows x 32 f32, swizzled
  __shared__ short Bsw[2][4096];   // 2 x 8 KB  : 8 packed bf16 frags

  const int kbeg = blockIdx.y * kc;
  const int nsteps = kc >> 5;

  // per-lane staging addresses
  const int seg_r = lane >> 3;             // row within an 8-row segment
  const int sunit = (lane & 7) ^ seg_r;    // pre-swizzled 16B unit
  const float* a_src0 = Am + (size_t)(m0 + seg_r) * NN + sunit * 4;
  const short* b_src0 = Xp + (size_t)lane * 8;

  #define STAGE(buf, k0)                                                      \
    {                                                                         \
      _Pragma("unroll")                                                       \
      for (int j = 0; j < 4; ++j) {                                           \
        int seg = w * 4 + j;                                                  \
        gll16(a_src0 + (size_t)(seg * 8) * NN + (k0), &Asw[buf][seg * 256]);  \
      }                                                                       \
      _Pragma("unroll")                                                       \
      for (int j = 0; j < 2; ++j) {                                           \
        int f = w * 2 + j;                                                    \
        gll16(b_src0 + (size_t)((k0) >> 5) * 4096 + f * 512,                  \
              &Bsw[buf][f * 512]);                                            \
      }                                                                       \
    }

  const int fr = lane & 15;
  const int q2 = (lane >> 4) * 2;          // 16B-unit base for this lane's k-cols
  const int wr = (w >> 1) * 64;
  const int wcn = (w & 1) * 4;             // base B-frag index (cols wcn*16..)

  f4 acc[4][4];
  #pragma unroll
  for (int i = 0; i < 4; i++)
    #pragma unroll
    for (int j = 0; j < 4; j++) acc[i][j] = (f4){0.f, 0.f, 0.f, 0.f};

  STAGE(0, kbeg);
  for (int it = 0; it < nsteps; ++it) {
    const int cur = it & 1;
    if (it + 1 < nsteps) {
      STAGE(cur ^ 1, kbeg + (it + 1) * 32);
      asm volatile("s_waitcnt vmcnt(6)" ::: "memory");
    } else {
      asm volatile("s_waitcnt vmcnt(0)" ::: "memory");
    }
    __builtin_amdgcn_s_barrier();
    __builtin_amdgcn_sched_barrier(0);   // pin reads below the barrier

    bfrag bb[4];
    #pragma unroll
    for (int j = 0; j < 4; ++j)
      bb[j] = *(const bfrag*)&Bsw[cur][(wcn + j) * 512 + lane * 8];
    #pragma unroll
    for (int i = 0; i < 4; ++i) {
      int row = wr + i * 16 + fr;
      int s = row & 7;
      const float* ab = &Asw[cur][row * 32];
      f4 x0 = *(const f4*)(ab + ((q2 ^ s) << 2));
      f4 x1 = *(const f4*)(ab + (((q2 + 1) ^ s) << 2));
      bfrag af;
      af[0] = f2bf(x0[0]); af[1] = f2bf(x0[1]); af[2] = f2bf(x0[2]); af[3] = f2bf(x0[3]);
      af[4] = f2bf(x1[0]); af[5] = f2bf(x1[1]); af[6] = f2bf(x1[2]); af[7] = f2bf(x1[3]);
      acc[i][0] = __builtin_amdgcn_mfma_f32_16x16x32_bf16(af, bb[0], acc[i][0], 0, 0, 0);
      acc[i][1] = __builtin_amdgcn_mfma_f32_16x16x32_bf16(af, bb[1], acc[i][1], 0, 0, 0);
      acc[i][2] = __builtin_amdgcn_mfma_f32_16x16x32_bf16(af, bb[2], acc[i][2], 0, 0, 0);
      acc[i][3] = __builtin_amdgcn_mfma_f32_16x16x32_bf16(af, bb[3], acc[i][3], 0, 0, 0);
    }
    __builtin_amdgcn_sched_barrier(0);   // keep compute above the closing barrier
    __builtin_amdgcn_s_barrier();
  }
  #undef STAGE

  float* outp = partials + (((size_t)g * ksplit + blockIdx.y) * NN + m0) * 128;
  const int crow = (lane >> 4) * 4;
  #pragma unroll
  for (int i = 0; i < 4; i++)
    #pragma unroll
    for (int j = 0; j < 4; j++) {
      float* p = outp + (size_t)(wr + i * 16 + crow) * 128 + wcn * 16 + j * 16 + fr;
      #pragma unroll
      for (int r = 0; r < 4; r++) p[(size_t)r * 128] = acc[i][j][r];
    }
}

// ---------------- reduce splits + bias + relu -> emb_g (g=0), emb_E (g=1)
__global__ __launch_bounds__(256) void reduce_kernel(
    const float* __restrict__ partials, const float* __restrict__ gcn_b,
    const float* __restrict__ gcnE_b, float* __restrict__ emb_g,
    float* __restrict__ emb_E, int ksplit) {
  int g = blockIdx.y;
  size_t i = ((size_t)blockIdx.x * 256 + threadIdx.x) * 4;
  const float* base = partials + (size_t)g * ksplit * NN * 128;
  f4 s = {0.f, 0.f, 0.f, 0.f};
  for (int sp = 0; sp < ksplit; ++sp)
    s += *(const f4*)(base + (size_t)sp * NN * 128 + i);
  const float* bias = g ? gcnE_b : gcn_b;
  f4 bv = *(const f4*)(bias + (i & 127));
  s += bv;
  s[0] = fmaxf(s[0], 0.f); s[1] = fmaxf(s[1], 0.f);
  s[2] = fmaxf(s[2], 0.f); s[3] = fmaxf(s[3], 0.f);
  float* outp = g ? emb_E : emb_g;
  *(f4*)(outp + i) = s;
}

// ---------------- fused attention + concat + final matmul ----------------
__global__ __launch_bounds__(128) void attn_kernel(
    const int* __restrict__ node_rd, const int* __restrict__ batch_node_idx,
    const float* __restrict__ Qa, const float* __restrict__ Ka,
    const float* __restrict__ Va, const float* __restrict__ tfn,
    const float* __restrict__ emb_g, const float* __restrict__ simi,
    const float* __restrict__ lin_W, const float* __restrict__ lin_b,
    float* __restrict__ outr) {
  int b = blockIdx.x;
  int t = threadIdx.x;
  __shared__ int idx[CTX1];
  __shared__ float tf0[64];
  __shared__ float qv[128];
  __shared__ float cosv[CTX1];
  __shared__ float sc[8][CTX1];
  __shared__ float femb[384];

  if (t < CTX1) idx[t] = node_rd[(size_t)b * CTX1 + t] + (t == 0 ? SRC : 0);
  __syncthreads();
  int i0 = idx[0];
  if (t < 64) tf0[t] = tfn[(size_t)i0 * 64 + t];
  qv[t] = Qa[(size_t)i0 * 128 + t];
  __syncthreads();

  {  // cos[c]: 4 lanes per context
    int c = t >> 2, q = t & 3;
    const float* tfc = tfn + (size_t)idx[c] * 64;
    float s = 0.f;
    #pragma unroll
    for (int j = 0; j < 16; j++) s += tf0[q + j * 4] * tfc[q + j * 4];
    s += __shfl_xor(s, 1);
    s += __shfl_xor(s, 2);
    if (q == 0) cosv[c] = s;
  }
  __syncthreads();

  // scores[h][c]
  for (int p = t; p < 256; p += 128) {
    int h = p >> 5, c = p & 31;
    const float* kp = Ka + (size_t)idx[c] * 128 + h * 16;
    float s = 0.f;
    #pragma unroll
    for (int d = 0; d < 16; d++) s += qv[h * 16 + d] * kp[d];
    sc[h][c] = s * 0.25f + cosv[c];
  }
  __syncthreads();

  {  // softmax over c, 16 lanes per head
    int h = t >> 4, l = t & 15;
    float s0 = sc[h][l], s1 = sc[h][l + 16];
    float m = fmaxf(s0, s1);
    #pragma unroll
    for (int o = 1; o < 16; o <<= 1) m = fmaxf(m, __shfl_xor(m, o));
    float e0 = expf(s0 - m), e1 = expf(s1 - m);
    float sum = e0 + e1;
    #pragma unroll
    for (int o = 1; o < 16; o <<= 1) sum += __shfl_xor(sum, o);
    float inv = 1.0f / sum;
    sc[h][l] = e0 * inv;
    sc[h][l + 16] = e1 * inv;
  }
  __syncthreads();

  {  // PV + elu
    int h = t >> 4, d = t & 15;
    float o = 0.f;
    #pragma unroll 4
    for (int c = 0; c < CTX1; c++)
      o += sc[h][c] * Va[(size_t)idx[c] * 128 + h * 16 + d];
    femb[128 + t] = (o > 0.f) ? o : expm1f(o);
  }
  int bn = batch_node_idx[b];
  femb[t] = emb_g[(size_t)bn * 128 + t];
  femb[256 + t] = simi[(size_t)b * 128 + t];
  __syncthreads();

  float accv = lin_b[t];
  #pragma unroll 8
  for (int j = 0; j < 384; j++) accv = fmaf(femb[j], lin_W[(size_t)j * 128 + t], accv);
  outr[(size_t)b * 128 + t] = accv;
}

// ---------------- loss ----------------
__global__ __launch_bounds__(256) void loss_kernel(
    const float* __restrict__ target, const float* __restrict__ result,
    float* __restrict__ out_loss) {
  int t = threadIdx.x;
  float s = 0.f;
  for (int b = t; b < BSZ; b += 256) {
    float d = target[(size_t)b * 128 + DROPC] - result[(size_t)b * 128 + DROPC];
    s += d * d;
  }
  #pragma unroll
  for (int o = 32; o > 0; o >>= 1) s += __shfl_xor(s, o);
  __shared__ float red[4];
  if ((t & 63) == 0) red[t >> 6] = s;
  __syncthreads();
  if (t == 0) out_loss[0] = (red[0] + red[1] + red[2] + red[3]) * (1.0f / BSZ);
}

extern "C" void kernel_launch(void* const* d_in, const int* in_sizes, int n_in,
                              void* d_out, int out_size, void* d_ws, size_t ws_size,
                              hipStream_t stream) {
  const float* adj = (const float*)d_in[0];
  const float* graphm = (const float*)d_in[1];
  const float* node_emb_gcn = (const float*)d_in[2];
  const float* trainfeature = (const float*)d_in[3];
  const float* target_emb = (const float*)d_in[4];
  const float* bsnf = (const float*)d_in[5];
  const int* batch_node_idx = (const int*)d_in[8];
  const int* node_rd = (const int*)d_in[9];
  const float* translate_W = (const float*)d_in[10];
  const float* translate_b = (const float*)d_in[11];
  const float* paraForCos = (const float*)d_in[12];
  const float* gcn_W = (const float*)d_in[13];
  const float* gcn_b = (const float*)d_in[14];
  const float* gcnE_W = (const float*)d_in[15];
  const float* gcnE_b = (const float*)d_in[16];
  const float* Wq = (const float*)d_in[17];
  const float* Wk = (const float*)d_in[18];
  const float* Wv = (const float*)d_in[19];
  const float* lin_W = (const float*)d_in[20];
  const float* lin_b = (const float*)d_in[21];

  char* ws = (char*)d_ws;
  size_t off = 0;
  auto alloc = [&](size_t bytes) {
    void* p = ws + off;
    off += (bytes + 255) & ~(size_t)255;
    return p;
  };
  short* XgP = (short*)alloc((size_t)128 * NN * 2);
  short* XEP = (short*)alloc((size_t)128 * NN * 2);
  float* tfn = (float*)alloc((size_t)NN * 64 * 4);
  float* wsum = (float*)alloc((size_t)BSZ * 128 * 4);
  float* simi = (float*)alloc((size_t)BSZ * 128 * 4);
  float* Qa = (float*)alloc((size_t)NN * 128 * 4);
  float* Ka = (float*)alloc((size_t)NN * 128 * 4);
  float* Va = (float*)alloc((size_t)NN * 128 * 4);
  float* emb_g = (float*)alloc((size_t)NN * 128 * 4);
  float* emb_E = (float*)alloc((size_t)NN * 128 * 4);
  float* meanpara = (float*)alloc(256);

  size_t per_split = 2ull * NN * 128 * 4;  // both gemms, one split = 8MB
  int ksplit = 1;
  if (off + 8 * per_split <= ws_size) ksplit = 8;
  else if (off + 4 * per_split <= ws_size) ksplit = 4;
  else if (off + 2 * per_split <= ws_size) ksplit = 2;
  float* partials = (float*)(ws + off);
  int kc = NN / ksplit;

  float* out_res = (float*)d_out;
  float* out_loss = out_res + (size_t)BSZ * 128;

  prep_kernel<<<4097, 256, 0, stream>>>(trainfeature, bsnf, paraForCos, tfn, wsum, meanpara);
  proj2_kernel<<<dim3(NN / 64, 2), 256, 0, stream>>>(node_emb_gcn, gcn_W, XgP,
                                                     trainfeature, gcnE_W, XEP);
  big_gemm_kernel<<<dim3(NN / 128, ksplit, 2), 256, 0, stream>>>(adj, graphm, XgP, XEP,
                                                                 partials, ksplit, kc);
  reduce_kernel<<<dim3(NN * 128 / (256 * 4), 2), 256, 0, stream>>>(partials, gcn_b, gcnE_b,
                                                                   emb_g, emb_E, ksplit);
  qkv_kernel<<<dim3(NN / 64, 3), 256, 0, stream>>>(emb_E, Wq, Wk, Wv, Qa, Ka, Va);
  gemm128_kernel<<<BSZ / 64, 256, 0, stream>>>(wsum, translate_W, translate_b, meanpara,
                                               simi, nullptr);
  attn_kernel<<<BSZ, 128, 0, stream>>>(node_rd, batch_node_idx, Qa, Ka, Va, tfn, emb_g,
                                       simi, lin_W, lin_b, out_res);
  loss_kernel<<<1, 256, 0, stream>>>(target_emb, out_res, out_loss);
}

// Round 5
// 269.101 us; speedup vs baseline: 1.2252x; 1.2252x over previous
//
#include <hip/hip_runtime.h>
#include <hip/hip_bf16.h>

#define NN 8192
#define ND 128
#define BSZ 4096
#define CTX1 32
#define SRC 4096
#define TOPK 8
#define DROPC 5

using f4 = __attribute__((ext_vector_type(4))) float;
using bfrag = __attribute__((ext_vector_type(8))) short;

__device__ __forceinline__ short f2bf(float x) {
  __hip_bfloat16 h = __float2bfloat16(x);
  return __builtin_bit_cast(short, h);
}

// ---------------- prep: tfn (normalized trainfeature[:, :64]), wsum, meanpara ----
__global__ __launch_bounds__(256) void prep_kernel(
    const float* __restrict__ trainfeature, const float* __restrict__ bsnf,
    const float* __restrict__ para, float* __restrict__ tfn,
    float* __restrict__ wsum, float* __restrict__ meanpara) {
  int blk = blockIdx.x;
  int t = threadIdx.x;
  if (blk < 2048) {                      // tfn: 4 rows per block, one wave per row
    int row = blk * 4 + (t >> 6);
    int j = t & 63;
    float x = trainfeature[(size_t)row * ND + j];
    float ss = x * x;
    #pragma unroll
    for (int o = 32; o > 0; o >>= 1) ss += __shfl_xor(ss, o);
    float nrm = sqrtf(ss) + 1e-8f;
    tfn[(size_t)row * 64 + j] = x / nrm;
  } else if (blk < 4096) {               // wsum: 2 rows per block
    int b = (blk - 2048) * 2 + (t >> 7);
    int k = t & 127;
    float s = 0.f;
    #pragma unroll
    for (int tt = 0; tt < TOPK; ++tt)
      s += para[tt] * bsnf[((size_t)b * TOPK + tt) * ND + k];
    wsum[(size_t)b * ND + k] = s * (1.0f / TOPK);
  } else {
    if (t == 0) {
      float s = 0.f;
      for (int tt = 0; tt < TOPK; ++tt) s += para[tt];
      *meanpara = s * (1.0f / TOPK);
    }
  }
}

// ---------------- generic f32 GEMM body: C[M][128] = A[M][128] @ W[128][128]
// Optional f32 output Cf. Optional bf16 MFMA-fragment-packed output Xpack:
// frag (kt,nt) is 64 lanes x 8 shorts contiguous (1KB); lane l, elem j holds
// X[kt*32 + (l>>4)*8 + j][nt*16 + (l&15)].
__device__ __forceinline__ void gemm128_body(
    const float* __restrict__ A, const float* __restrict__ W,
    const float* __restrict__ bias, const float* __restrict__ bscale_ptr,
    float* __restrict__ Cf, short* __restrict__ Xpack, int row0) {
  __shared__ float Ws[128][132];
  __shared__ float As[64][128];
  int t = threadIdx.x;
  for (int i = t; i < 128 * 32; i += 256) {
    int r = i >> 5, c = (i & 31) * 4;
    *(f4*)&Ws[r][c] = *(const f4*)&W[(size_t)r * 128 + c];
  }
  for (int i = t; i < 64 * 32; i += 256) {
    int r = i >> 5, c = (i & 31) * 4;
    *(f4*)&As[r][c] = *(const f4*)&A[(size_t)(row0 + r) * 128 + c];
  }
  __syncthreads();
  int tr = (t >> 5) * 8;
  int tc = (t & 31) * 4;
  float acc[8][4];
  #pragma unroll
  for (int i = 0; i < 8; i++)
    #pragma unroll
    for (int j = 0; j < 4; j++) acc[i][j] = 0.f;
  for (int k = 0; k < 128; k++) {
    f4 w = *(const f4*)&Ws[k][tc];
    #pragma unroll
    for (int i = 0; i < 8; i++) {
      float a = As[tr + i][k];
      acc[i][0] = fmaf(a, w[0], acc[i][0]);
      acc[i][1] = fmaf(a, w[1], acc[i][1]);
      acc[i][2] = fmaf(a, w[2], acc[i][2]);
      acc[i][3] = fmaf(a, w[3], acc[i][3]);
    }
  }
  if (bias) {
    float bsc = bscale_ptr ? *bscale_ptr : 1.0f;
    #pragma unroll
    for (int i = 0; i < 8; i++)
      #pragma unroll
      for (int j = 0; j < 4; j++) acc[i][j] += bias[tc + j] * bsc;
  }
  if (Cf) {
    #pragma unroll
    for (int i = 0; i < 8; i++) {
      int r = row0 + tr + i;
      #pragma unroll
      for (int j = 0; j < 4; j++) Cf[(size_t)r * 128 + tc + j] = acc[i][j];
    }
  }
  if (Xpack) {
    int kb = row0 + tr;              // multiple of 8
    int kt = kb >> 5;
    int lane_hi = (kb >> 3) & 3;
    #pragma unroll
    for (int j = 0; j < 4; j++) {
      int n = tc + j;
      int ln = (n & 15) | (lane_hi << 4);
      bfrag h;
      #pragma unroll
      for (int i = 0; i < 8; i++) h[i] = f2bf(acc[i][j]);
      *(bfrag*)&Xpack[((size_t)(kt * 8 + (n >> 4)) * 64 + ln) * 8] = h;
    }
  }
}

__global__ __launch_bounds__(256) void gemm128_kernel(
    const float* __restrict__ A, const float* __restrict__ W,
    const float* __restrict__ bias, const float* __restrict__ bscale_ptr,
    float* __restrict__ Cf, short* __restrict__ Xpack) {
  gemm128_body(A, W, bias, bscale_ptr, Cf, Xpack, blockIdx.x * 64);
}

// 2 projections in one launch, writing MFMA-packed bf16
__global__ __launch_bounds__(256) void proj2_kernel(
    const float* __restrict__ A0, const float* __restrict__ W0, short* __restrict__ T0,
    const float* __restrict__ A1, const float* __restrict__ W1, short* __restrict__ T1) {
  if (blockIdx.y == 0)
    gemm128_body(A0, W0, nullptr, nullptr, nullptr, T0, blockIdx.x * 64);
  else
    gemm128_body(A1, W1, nullptr, nullptr, nullptr, T1, blockIdx.x * 64);
}

// QKV in one launch
__global__ __launch_bounds__(256) void qkv_kernel(
    const float* __restrict__ A, const float* __restrict__ Wq,
    const float* __restrict__ Wk, const float* __restrict__ Wv,
    float* __restrict__ Qa, float* __restrict__ Ka, float* __restrict__ Va) {
  const float* W = blockIdx.y == 0 ? Wq : (blockIdx.y == 1 ? Wk : Wv);
  float* C = blockIdx.y == 0 ? Qa : (blockIdx.y == 1 ? Ka : Va);
  gemm128_body(A, W, nullptr, nullptr, C, nullptr, blockIdx.x * 64);
}

// ---------------- big GEMM (merged):
//  blockIdx.x <  64 : partialsE[split] += graph[rows m0..m0+128] @ XEP
//  blockIdx.x >= 64 : partialsG[split] += adj[batch_node_idx[p]] @ XgP (gathered)
// Reg-pipelined, no LDS/barriers. K-loop DE-PHASED per block: each block walks
// its 64-K chunks starting at a block-dependent rotation so the chip-wide
// address stream covers all HBM channels (break the 32KB-stride low-bit lock).
struct Step {
  f4 a00, a01, a10, a11;
  bfrag b0, b1, b2, b3, b4, b5, b6, b7;
};

__global__ __launch_bounds__(256, 2) void big_gemm_kernel(
    const float* __restrict__ adj, const float* __restrict__ graphm,
    const short* __restrict__ XgP, const short* __restrict__ XEP,
    const int* __restrict__ bni,
    float* __restrict__ partialsE, float* __restrict__ partialsG,
    int ksplit, int kc) {
  const int bx = blockIdx.x;
  const bool isG = bx >= 64;             // gathered adj part
  const int t = threadIdx.x;
  const int lane = t & 63;
  const int w = t >> 6;

  const float* __restrict__ Am = isG ? adj : graphm;
  const short* __restrict__ Xp = isG ? XgP : XEP;
  const int m0 = (isG ? (bx - 64) : bx) * 128;

  const int p0 = m0 + w * 32 + (lane & 15);
  const int row0 = isG ? bni[p0] : p0;
  const int row1 = isG ? bni[p0 + 16] : p0 + 16;
  const int koff = (lane >> 4) * 8;
  const float* Ap0 = Am + (size_t)row0 * NN + koff;
  const float* Ap1 = Am + (size_t)row1 * NN + koff;
  const short* Xb = Xp + (size_t)lane * 8;

  const int kbeg = blockIdx.y * kc;
  const int CH = kc >> 6;                // 64-K chunks (power of 2)
  const int phase = (bx * 5 + blockIdx.y * 3) & (CH - 1);

  Step s0, s1;
  auto load = [&](Step& s, int k0) {
    const float* pa = Ap0 + k0;
    s.a00 = *(const f4*)(pa);
    s.a01 = *(const f4*)(pa + 4);
    const float* pb = Ap1 + k0;
    s.a10 = *(const f4*)(pb);
    s.a11 = *(const f4*)(pb + 4);
    const short* xq = Xb + (size_t)(k0 >> 5) * 4096;
    s.b0 = *(const bfrag*)(xq);
    s.b1 = *(const bfrag*)(xq + 512);
    s.b2 = *(const bfrag*)(xq + 1024);
    s.b3 = *(const bfrag*)(xq + 1536);
    s.b4 = *(const bfrag*)(xq + 2048);
    s.b5 = *(const bfrag*)(xq + 2560);
    s.b6 = *(const bfrag*)(xq + 3072);
    s.b7 = *(const bfrag*)(xq + 3584);
  };

  f4 acc0[8], acc1[8];
  #pragma unroll
  for (int i = 0; i < 8; i++) {
    acc0[i] = (f4){0.f, 0.f, 0.f, 0.f};
    acc1[i] = (f4){0.f, 0.f, 0.f, 0.f};
  }

  auto compute = [&](Step& s) {
    bfrag af0, af1;
    af0[0] = f2bf(s.a00[0]); af0[1] = f2bf(s.a00[1]);
    af0[2] = f2bf(s.a00[2]); af0[3] = f2bf(s.a00[3]);
    af0[4] = f2bf(s.a01[0]); af0[5] = f2bf(s.a01[1]);
    af0[6] = f2bf(s.a01[2]); af0[7] = f2bf(s.a01[3]);
    af1[0] = f2bf(s.a10[0]); af1[1] = f2bf(s.a10[1]);
    af1[2] = f2bf(s.a10[2]); af1[3] = f2bf(s.a10[3]);
    af1[4] = f2bf(s.a11[0]); af1[5] = f2bf(s.a11[1]);
    af1[6] = f2bf(s.a11[2]); af1[7] = f2bf(s.a11[3]);
    acc0[0] = __builtin_amdgcn_mfma_f32_16x16x32_bf16(af0, s.b0, acc0[0], 0, 0, 0);
    acc1[0] = __builtin_amdgcn_mfma_f32_16x16x32_bf16(af1, s.b0, acc1[0], 0, 0, 0);
    acc0[1] = __builtin_amdgcn_mfma_f32_16x16x32_bf16(af0, s.b1, acc0[1], 0, 0, 0);
    acc1[1] = __builtin_amdgcn_mfma_f32_16x16x32_bf16(af1, s.b1, acc1[1], 0, 0, 0);
    acc0[2] = __builtin_amdgcn_mfma_f32_16x16x32_bf16(af0, s.b2, acc0[2], 0, 0, 0);
    acc1[2] = __builtin_amdgcn_mfma_f32_16x16x32_bf16(af1, s.b2, acc1[2], 0, 0, 0);
    acc0[3] = __builtin_amdgcn_mfma_f32_16x16x32_bf16(af0, s.b3, acc0[3], 0, 0, 0);
    acc1[3] = __builtin_amdgcn_mfma_f32_16x16x32_bf16(af1, s.b3, acc1[3], 0, 0, 0);
    acc0[4] = __builtin_amdgcn_mfma_f32_16x16x32_bf16(af0, s.b4, acc0[4], 0, 0, 0);
    acc1[4] = __builtin_amdgcn_mfma_f32_16x16x32_bf16(af1, s.b4, acc1[4], 0, 0, 0);
    acc0[5] = __builtin_amdgcn_mfma_f32_16x16x32_bf16(af0, s.b5, acc0[5], 0, 0, 0);
    acc1[5] = __builtin_amdgcn_mfma_f32_16x16x32_bf16(af1, s.b5, acc1[5], 0, 0, 0);
    acc0[6] = __builtin_amdgcn_mfma_f32_16x16x32_bf16(af0, s.b6, acc0[6], 0, 0, 0);
    acc1[6] = __builtin_amdgcn_mfma_f32_16x16x32_bf16(af1, s.b6, acc1[6], 0, 0, 0);
    acc0[7] = __builtin_amdgcn_mfma_f32_16x16x32_bf16(af0, s.b7, acc0[7], 0, 0, 0);
    acc1[7] = __builtin_amdgcn_mfma_f32_16x16x32_bf16(af1, s.b7, acc1[7], 0, 0, 0);
  };

  auto kof = [&](int c) { return kbeg + ((phase + c) & (CH - 1)) * 64; };

  load(s0, kof(0));
  load(s1, kof(0) + 32);
  for (int c = 0; c < CH; ++c) {
    compute(s0);
    if (c + 1 < CH) load(s0, kof(c + 1));
    compute(s1);
    if (c + 1 < CH) load(s1, kof(c + 1) + 32);
  }

  float* outp = (isG ? partialsG + ((size_t)blockIdx.y * 4096 + m0) * 128
                     : partialsE + ((size_t)blockIdx.y * NN + m0) * 128);
  const int crow = (lane >> 4) * 4;
  const int ccol = lane & 15;
  #pragma unroll
  for (int nt = 0; nt < 8; nt++) {
    #pragma unroll
    for (int r = 0; r < 4; r++) {
      outp[(size_t)(w * 32 + crow + r) * 128 + nt * 16 + ccol] = acc0[nt][r];
      outp[(size_t)(w * 32 + 16 + crow + r) * 128 + nt * 16 + ccol] = acc1[nt][r];
    }
  }
}

// ---------------- reduce splits + bias + relu
// g=0: emb_E[8192][128] from partialsE; g=1: emb_gb[4096][128] from partialsG
__global__ __launch_bounds__(256) void reduce_kernel(
    const float* __restrict__ partialsE, const float* __restrict__ partialsG,
    const float* __restrict__ gcnE_b, const float* __restrict__ gcn_b,
    float* __restrict__ emb_E, float* __restrict__ emb_gb, int ksplit) {
  int g = blockIdx.y;
  if (g == 1 && blockIdx.x >= 512) return;
  size_t i = ((size_t)blockIdx.x * 256 + threadIdx.x) * 4;
  const float* base = g ? partialsG : partialsE;
  const size_t stride = (size_t)(g ? 4096 : NN) * 128;
  f4 s = {0.f, 0.f, 0.f, 0.f};
  for (int sp = 0; sp < ksplit; ++sp)
    s += *(const f4*)(base + (size_t)sp * stride + i);
  const float* bias = g ? gcn_b : gcnE_b;
  f4 bv = *(const f4*)(bias + (i & 127));
  s += bv;
  s[0] = fmaxf(s[0], 0.f); s[1] = fmaxf(s[1], 0.f);
  s[2] = fmaxf(s[2], 0.f); s[3] = fmaxf(s[3], 0.f);
  float* outp = g ? emb_gb : emb_E;
  *(f4*)(outp + i) = s;
}

// ---------------- fused attention + concat + final matmul ----------------
__global__ __launch_bounds__(128) void attn_kernel(
    const int* __restrict__ node_rd,
    const float* __restrict__ Qa, const float* __restrict__ Ka,
    const float* __restrict__ Va, const float* __restrict__ tfn,
    const float* __restrict__ emb_gb, const float* __restrict__ simi,
    const float* __restrict__ lin_W, const float* __restrict__ lin_b,
    float* __restrict__ outr) {
  int b = blockIdx.x;
  int t = threadIdx.x;
  __shared__ int idx[CTX1];
  __shared__ float tf0[64];
  __shared__ float qv[128];
  __shared__ float cosv[CTX1];
  __shared__ float sc[8][CTX1];
  __shared__ float femb[384];

  if (t < CTX1) idx[t] = node_rd[(size_t)b * CTX1 + t] + (t == 0 ? SRC : 0);
  __syncthreads();
  int i0 = idx[0];
  if (t < 64) tf0[t] = tfn[(size_t)i0 * 64 + t];
  qv[t] = Qa[(size_t)i0 * 128 + t];
  __syncthreads();

  {  // cos[c]: 4 lanes per context
    int c = t >> 2, q = t & 3;
    const float* tfc = tfn + (size_t)idx[c] * 64;
    float s = 0.f;
    #pragma unroll
    for (int j = 0; j < 16; j++) s += tf0[q + j * 4] * tfc[q + j * 4];
    s += __shfl_xor(s, 1);
    s += __shfl_xor(s, 2);
    if (q == 0) cosv[c] = s;
  }
  __syncthreads();

  // scores[h][c]
  for (int p = t; p < 256; p += 128) {
    int h = p >> 5, c = p & 31;
    const float* kp = Ka + (size_t)idx[c] * 128 + h * 16;
    float s = 0.f;
    #pragma unroll
    for (int d = 0; d < 16; d++) s += qv[h * 16 + d] * kp[d];
    sc[h][c] = s * 0.25f + cosv[c];
  }
  __syncthreads();

  {  // softmax over c, 16 lanes per head
    int h = t >> 4, l = t & 15;
    float s0 = sc[h][l], s1 = sc[h][l + 16];
    float m = fmaxf(s0, s1);
    #pragma unroll
    for (int o = 1; o < 16; o <<= 1) m = fmaxf(m, __shfl_xor(m, o));
    float e0 = expf(s0 - m), e1 = expf(s1 - m);
    float sum = e0 + e1;
    #pragma unroll
    for (int o = 1; o < 16; o <<= 1) sum += __shfl_xor(sum, o);
    float inv = 1.0f / sum;
    sc[h][l] = e0 * inv;
    sc[h][l + 16] = e1 * inv;
  }
  __syncthreads();

  {  // PV + elu
    int h = t >> 4, d = t & 15;
    float o = 0.f;
    #pragma unroll 4
    for (int c = 0; c < CTX1; c++)
      o += sc[h][c] * Va[(size_t)idx[c] * 128 + h * 16 + d];
    femb[128 + t] = (o > 0.f) ? o : expm1f(o);
  }
  femb[t] = emb_gb[(size_t)b * 128 + t];
  femb[256 + t] = simi[(size_t)b * 128 + t];
  __syncthreads();

  float accv = lin_b[t];
  #pragma unroll 8
  for (int j = 0; j < 384; j++) accv = fmaf(femb[j], lin_W[(size_t)j * 128 + t], accv);
  outr[(size_t)b * 128 + t] = accv;
}

// ---------------- loss ----------------
__global__ __launch_bounds__(256) void loss_kernel(
    const float* __restrict__ target, const float* __restrict__ result,
    float* __restrict__ out_loss) {
  int t = threadIdx.x;
  float s = 0.f;
  for (int b = t; b < BSZ; b += 256) {
    float d = target[(size_t)b * 128 + DROPC] - result[(size_t)b * 128 + DROPC];
    s += d * d;
  }
  #pragma unroll
  for (int o = 32; o > 0; o >>= 1) s += __shfl_xor(s, o);
  __shared__ float red[4];
  if ((t & 63) == 0) red[t >> 6] = s;
  __syncthreads();
  if (t == 0) out_loss[0] = (red[0] + red[1] + red[2] + red[3]) * (1.0f / BSZ);
}

extern "C" void kernel_launch(void* const* d_in, const int* in_sizes, int n_in,
                              void* d_out, int out_size, void* d_ws, size_t ws_size,
                              hipStream_t stream) {
  const float* adj = (const float*)d_in[0];
  const float* graphm = (const float*)d_in[1];
  const float* node_emb_gcn = (const float*)d_in[2];
  const float* trainfeature = (const float*)d_in[3];
  const float* target_emb = (const float*)d_in[4];
  const float* bsnf = (const float*)d_in[5];
  const int* batch_node_idx = (const int*)d_in[8];
  const int* node_rd = (const int*)d_in[9];
  const float* translate_W = (const float*)d_in[10];
  const float* translate_b = (const float*)d_in[11];
  const float* paraForCos = (const float*)d_in[12];
  const float* gcn_W = (const float*)d_in[13];
  const float* gcn_b = (const float*)d_in[14];
  const float* gcnE_W = (const float*)d_in[15];
  const float* gcnE_b = (const float*)d_in[16];
  const float* Wq = (const float*)d_in[17];
  const float* Wk = (const float*)d_in[18];
  const float* Wv = (const float*)d_in[19];
  const float* lin_W = (const float*)d_in[20];
  const float* lin_b = (const float*)d_in[21];

  char* ws = (char*)d_ws;
  size_t off = 0;
  auto alloc = [&](size_t bytes) {
    void* p = ws + off;
    off += (bytes + 255) & ~(size_t)255;
    return p;
  };
  short* XgP = (short*)alloc((size_t)128 * NN * 2);
  short* XEP = (short*)alloc((size_t)128 * NN * 2);
  float* tfn = (float*)alloc((size_t)NN * 64 * 4);
  float* wsum = (float*)alloc((size_t)BSZ * 128 * 4);
  float* simi = (float*)alloc((size_t)BSZ * 128 * 4);
  float* Qa = (float*)alloc((size_t)NN * 128 * 4);
  float* Ka = (float*)alloc((size_t)NN * 128 * 4);
  float* Va = (float*)alloc((size_t)NN * 128 * 4);
  float* emb_E = (float*)alloc((size_t)NN * 128 * 4);
  float* emb_gb = (float*)alloc((size_t)BSZ * 128 * 4);
  float* meanpara = (float*)alloc(256);

  size_t per_split = (size_t)(NN + BSZ) * 128 * 4;  // E + G partials = 6MB/split
  int ksplit = 1;
  if (off + 8 * per_split <= ws_size) ksplit = 8;
  else if (off + 4 * per_split <= ws_size) ksplit = 4;
  else if (off + 2 * per_split <= ws_size) ksplit = 2;
  float* partialsE = (float*)(ws + off);
  float* partialsG = partialsE + (size_t)ksplit * NN * 128;
  int kc = NN / ksplit;

  float* out_res = (float*)d_out;
  float* out_loss = out_res + (size_t)BSZ * 128;

  prep_kernel<<<4097, 256, 0, stream>>>(trainfeature, bsnf, paraForCos, tfn, wsum, meanpara);
  proj2_kernel<<<dim3(NN / 64, 2), 256, 0, stream>>>(node_emb_gcn, gcn_W, XgP,
                                                     trainfeature, gcnE_W, XEP);
  big_gemm_kernel<<<dim3(96, ksplit), 256, 0, stream>>>(adj, graphm, XgP, XEP,
                                                        batch_node_idx, partialsE,
                                                        partialsG, ksplit, kc);
  reduce_kernel<<<dim3(1024, 2), 256, 0, stream>>>(partialsE, partialsG, gcnE_b, gcn_b,
                                                   emb_E, emb_gb, ksplit);
  qkv_kernel<<<dim3(NN / 64, 3), 256, 0, stream>>>(emb_E, Wq, Wk, Wv, Qa, Ka, Va);
  gemm128_kernel<<<BSZ / 64, 256, 0, stream>>>(wsum, translate_W, translate_b, meanpara,
                                               simi, nullptr);
  attn_kernel<<<BSZ, 128, 0, stream>>>(node_rd, Qa, Ka, Va, tfn, emb_gb,
                                       simi, lin_W, lin_b, out_res);
  loss_kernel<<<1, 256, 0, stream>>>(target_emb, out_res, out_loss);
}

// Round 6
// 262.081 us; speedup vs baseline: 1.2580x; 1.0268x over previous
//
#include <hip/hip_runtime.h>
#include <hip/hip_bf16.h>

#define NN 8192
#define ND 128
#define BSZ 4096
#define CTX1 32
#define SRC 4096
#define TOPK 8
#define DROPC 5

#define BM 16          // rows per big_gemm block
#define BKC 512        // K floats per macro-step (2KB per row burst)
#define NMS (NN / BKC) // 16 macro-steps

using f4 = __attribute__((ext_vector_type(4))) float;
using bfrag = __attribute__((ext_vector_type(8))) short;

__device__ __forceinline__ short f2bf(float x) {
  __hip_bfloat16 h = __float2bfloat16(x);
  return __builtin_bit_cast(short, h);
}

// ---------------- prep: tfn, wsum, meanpara, lin_W bf16 frag-pack ----
__global__ __launch_bounds__(256) void prep_kernel(
    const float* __restrict__ trainfeature, const float* __restrict__ bsnf,
    const float* __restrict__ para, const float* __restrict__ lin_W,
    float* __restrict__ tfn, float* __restrict__ wsum,
    float* __restrict__ meanpara, short* __restrict__ linWp) {
  int blk = blockIdx.x;
  int t = threadIdx.x;
  if (blk < 2048) {                      // tfn: 4 rows per block, one wave per row
    int row = blk * 4 + (t >> 6);
    int j = t & 63;
    float x = trainfeature[(size_t)row * ND + j];
    float ss = x * x;
    #pragma unroll
    for (int o = 32; o > 0; o >>= 1) ss += __shfl_xor(ss, o);
    float nrm = sqrtf(ss) + 1e-8f;
    tfn[(size_t)row * 64 + j] = x / nrm;
  } else if (blk < 4096) {               // wsum: 2 rows per block
    int b = (blk - 2048) * 2 + (t >> 7);
    int k = t & 127;
    float s = 0.f;
    #pragma unroll
    for (int tt = 0; tt < TOPK; ++tt)
      s += para[tt] * bsnf[((size_t)b * TOPK + tt) * ND + k];
    wsum[(size_t)b * ND + k] = s * (1.0f / TOPK);
  } else if (blk == 4096) {
    if (t == 0) {
      float s = 0.f;
      for (int tt = 0; tt < TOPK; ++tt) s += para[tt];
      *meanpara = s * (1.0f / TOPK);
    }
  } else {                               // lin_W pack: blk 4097..4108 -> kt 0..11
    int kt = blk - 4097;
    #pragma unroll
    for (int q = 0; q < 16; ++q) {
      int e = t * 16 + q;
      int nt = e >> 9, lane = (e >> 3) & 63, j = e & 7;
      float v = lin_W[(size_t)(kt * 32 + (lane >> 4) * 8 + j) * 128 + nt * 16 + (lane & 15)];
      linWp[(size_t)kt * 4096 + e] = f2bf(v);
    }
  }
}

// ---------------- generic f32 GEMM body: C[M][128] = A[M][128] @ W[128][128]
// Optional f32 output Cf. Optional bf16 MFMA-fragment-packed output Xpack:
// frag (kt,nt) is 64 lanes x 8 shorts contiguous; lane l, elem j holds
// X[kt*32 + (l>>4)*8 + j][nt*16 + (l&15)].
__device__ __forceinline__ void gemm128_body(
    const float* __restrict__ A, const float* __restrict__ W,
    const float* __restrict__ bias, const float* __restrict__ bscale_ptr,
    float* __restrict__ Cf, short* __restrict__ Xpack, int row0) {
  __shared__ float Ws[128][132];
  __shared__ float As[64][128];
  int t = threadIdx.x;
  for (int i = t; i < 128 * 32; i += 256) {
    int r = i >> 5, c = (i & 31) * 4;
    *(f4*)&Ws[r][c] = *(const f4*)&W[(size_t)r * 128 + c];
  }
  for (int i = t; i < 64 * 32; i += 256) {
    int r = i >> 5, c = (i & 31) * 4;
    *(f4*)&As[r][c] = *(const f4*)&A[(size_t)(row0 + r) * 128 + c];
  }
  __syncthreads();
  int tr = (t >> 5) * 8;
  int tc = (t & 31) * 4;
  float acc[8][4];
  #pragma unroll
  for (int i = 0; i < 8; i++)
    #pragma unroll
    for (int j = 0; j < 4; j++) acc[i][j] = 0.f;
  for (int k = 0; k < 128; k++) {
    f4 w = *(const f4*)&Ws[k][tc];
    #pragma unroll
    for (int i = 0; i < 8; i++) {
      float a = As[tr + i][k];
      acc[i][0] = fmaf(a, w[0], acc[i][0]);
      acc[i][1] = fmaf(a, w[1], acc[i][1]);
      acc[i][2] = fmaf(a, w[2], acc[i][2]);
      acc[i][3] = fmaf(a, w[3], acc[i][3]);
    }
  }
  if (bias) {
    float bsc = bscale_ptr ? *bscale_ptr : 1.0f;
    #pragma unroll
    for (int i = 0; i < 8; i++)
      #pragma unroll
      for (int j = 0; j < 4; j++) acc[i][j] += bias[tc + j] * bsc;
  }
  if (Cf) {
    #pragma unroll
    for (int i = 0; i < 8; i++) {
      int r = row0 + tr + i;
      #pragma unroll
      for (int j = 0; j < 4; j++) Cf[(size_t)r * 128 + tc + j] = acc[i][j];
    }
  }
  if (Xpack) {
    int kb = row0 + tr;              // multiple of 8
    int kt = kb >> 5;
    int lane_hi = (kb >> 3) & 3;
    #pragma unroll
    for (int j = 0; j < 4; j++) {
      int n = tc + j;
      int ln = (n & 15) | (lane_hi << 4);
      bfrag h;
      #pragma unroll
      for (int i = 0; i < 8; i++) h[i] = f2bf(acc[i][j]);
      *(bfrag*)&Xpack[((size_t)(kt * 8 + (n >> 4)) * 64 + ln) * 8] = h;
    }
  }
}

__global__ __launch_bounds__(256) void gemm128_kernel(
    const float* __restrict__ A, const float* __restrict__ W,
    const float* __restrict__ bias, const float* __restrict__ bscale_ptr,
    float* __restrict__ Cf, short* __restrict__ Xpack) {
  gemm128_body(A, W, bias, bscale_ptr, Cf, Xpack, blockIdx.x * 64);
}

// 2 projections in one launch, writing MFMA-packed bf16
__global__ __launch_bounds__(256) void proj2_kernel(
    const float* __restrict__ A0, const float* __restrict__ W0, short* __restrict__ T0,
    const float* __restrict__ A1, const float* __restrict__ W1, short* __restrict__ T1) {
  if (blockIdx.y == 0)
    gemm128_body(A0, W0, nullptr, nullptr, nullptr, T0, blockIdx.x * 64);
  else
    gemm128_body(A1, W1, nullptr, nullptr, nullptr, T1, blockIdx.x * 64);
}

// QKV in one launch
__global__ __launch_bounds__(256) void qkv_kernel(
    const float* __restrict__ A, const float* __restrict__ Wq,
    const float* __restrict__ Wk, const float* __restrict__ Wv,
    float* __restrict__ Qa, float* __restrict__ Ka, float* __restrict__ Va) {
  const float* W = blockIdx.y == 0 ? Wq : (blockIdx.y == 1 ? Wk : Wv);
  float* C = blockIdx.y == 0 ? Qa : (blockIdx.y == 1 ? Ka : Va);
  gemm128_body(A, W, nullptr, nullptr, C, nullptr, blockIdx.x * 64);
}

// ---------------- big GEMM, DRAM-page-friendly:
//  bx < 512 : emb_E[m0..m0+16]  = relu(graph rows @ XEP + gcnE_b)
//  bx >= 512: emb_gb[p0..p0+16] = relu(adj[bni[p]] @ XgP + gcn_b)
// Each block streams 16 rows in 2KB contiguous bursts (BKC=512 f32/row/step),
// reg-stages, converts to bf16 into XOR-swizzled LDS, MFMA over 16 k-steps.
// One barrier per macro-step; next-step loads issued AFTER the barrier so
// __syncthreads' vmcnt(0) drain cannot touch them.
__global__ __launch_bounds__(256, 4) void big_gemm_kernel(
    const float* __restrict__ adj, const float* __restrict__ graphm,
    const short* __restrict__ XgP, const short* __restrict__ XEP,
    const int* __restrict__ bni,
    const float* __restrict__ gcnE_b, const float* __restrict__ gcn_b,
    float* __restrict__ emb_E, float* __restrict__ emb_gb) {
  const int bx = blockIdx.x;
  const bool isG = bx >= 512;
  const int t = threadIdx.x;
  const int lane = t & 63;
  const int w = t >> 6;

  const float* __restrict__ Am = isG ? adj : graphm;
  const short* __restrict__ Xp = isG ? XgP : XEP;
  const int m0 = (isG ? bx - 512 : bx) * BM;

  // staging map: row sr = t>>4, 128B contiguous chunk ss = t&15
  const int sr = t >> 4;
  const int ss = t & 15;
  int grow = m0 + sr;
  if (isG) grow = bni[grow];
  const float* gsrc = Am + (size_t)grow * NN + ss * 32;

  __shared__ short Abuf[2][BM * BKC];    // 2 x 16KB bf16, XOR-swizzled units

  const int fr = lane & 15;              // A row within tile
  const int kq = lane >> 4;              // k-quarter
  const short* Xb = Xp + (size_t)lane * 8;

  f4 acc0 = {0.f, 0.f, 0.f, 0.f}, acc1 = {0.f, 0.f, 0.f, 0.f};
  f4 st[8];
  #pragma unroll
  for (int i = 0; i < 8; i++) st[i] = *(const f4*)(gsrc + i * 4);

  for (int ms = 0; ms < NMS; ++ms) {
    const int cur = ms & 1;
    // convert + swizzled ds_write (implicit vmcnt wait on st loads)
    {
      short* rb = &Abuf[cur][sr * BKC];
      #pragma unroll
      for (int j = 0; j < 4; ++j) {
        bfrag h;
        #pragma unroll
        for (int e = 0; e < 8; ++e) h[e] = f2bf(st[j * 2 + (e >> 2)][e & 3]);
        int u_sw = (ss * 4 + j) ^ (sr & 7);
        *(bfrag*)&rb[u_sw * 8] = h;
      }
    }
    __syncthreads();
    if (ms + 1 < NMS) {
      const float* g2 = gsrc + (size_t)(ms + 1) * BKC;
      #pragma unroll
      for (int i = 0; i < 8; i++) st[i] = *(const f4*)(g2 + i * 4);
    }
    // compute 16 k-steps on Abuf[cur]
    #pragma unroll
    for (int ks = 0; ks < 16; ++ks) {
      int u_sw = (ks * 4 + kq) ^ (fr & 7);
      bfrag a = *(const bfrag*)&Abuf[cur][fr * BKC + u_sw * 8];
      const short* xq = Xb + (size_t)(ms * 16 + ks) * 4096;
      bfrag b0 = *(const bfrag*)(xq + (2 * w) * 512);
      bfrag b1 = *(const bfrag*)(xq + (2 * w + 1) * 512);
      acc0 = __builtin_amdgcn_mfma_f32_16x16x32_bf16(a, b0, acc0, 0, 0, 0);
      acc1 = __builtin_amdgcn_mfma_f32_16x16x32_bf16(a, b1, acc1, 0, 0, 0);
    }
    // no trailing barrier needed: double-buffer + the single barrier per step
    // already orders write(i+2) after compute(i) (barrier i+1 dominates).
  }

  // epilogue: bias + relu, write output
  const float* bias = isG ? gcn_b : gcnE_b;
  float* outp = isG ? emb_gb : emb_E;
  const int orow = (isG ? bx - 512 : bx) * BM + kq * 4;
  #pragma unroll
  for (int r = 0; r < 4; ++r) {
    int n0 = 2 * w * 16 + fr;
    float v0 = fmaxf(acc0[r] + bias[n0], 0.f);
    float v1 = fmaxf(acc1[r] + bias[n0 + 16], 0.f);
    outp[(size_t)(orow + r) * 128 + n0] = v0;
    outp[(size_t)(orow + r) * 128 + n0 + 16] = v1;
  }
}

// ---------------- fused attention: writes femb (bf16 [BSZ][384]) ----------------
__global__ __launch_bounds__(128) void attn_kernel(
    const int* __restrict__ node_rd,
    const float* __restrict__ Qa, const float* __restrict__ Ka,
    const float* __restrict__ Va, const float* __restrict__ tfn,
    const float* __restrict__ emb_gb, const float* __restrict__ simi,
    short* __restrict__ femb_bf) {
  int b = blockIdx.x;
  int t = threadIdx.x;
  __shared__ int idx[CTX1];
  __shared__ float tf0[64];
  __shared__ float qv[128];
  __shared__ float cosv[CTX1];
  __shared__ float sc[8][CTX1];

  if (t < CTX1) idx[t] = node_rd[(size_t)b * CTX1 + t] + (t == 0 ? SRC : 0);
  __syncthreads();
  int i0 = idx[0];
  if (t < 64) tf0[t] = tfn[(size_t)i0 * 64 + t];
  qv[t] = Qa[(size_t)i0 * 128 + t];
  __syncthreads();

  {  // cos[c]: 4 lanes per context
    int c = t >> 2, q = t & 3;
    const float* tfc = tfn + (size_t)idx[c] * 64;
    float s = 0.f;
    #pragma unroll
    for (int j = 0; j < 16; j++) s += tf0[q + j * 4] * tfc[q + j * 4];
    s += __shfl_xor(s, 1);
    s += __shfl_xor(s, 2);
    if (q == 0) cosv[c] = s;
  }
  __syncthreads();

  // scores[h][c]
  for (int p = t; p < 256; p += 128) {
    int h = p >> 5, c = p & 31;
    const float* kp = Ka + (size_t)idx[c] * 128 + h * 16;
    float s = 0.f;
    #pragma unroll
    for (int d = 0; d < 16; d++) s += qv[h * 16 + d] * kp[d];
    sc[h][c] = s * 0.25f + cosv[c];
  }
  __syncthreads();

  {  // softmax over c, 16 lanes per head
    int h = t >> 4, l = t & 15;
    float s0 = sc[h][l], s1 = sc[h][l + 16];
    float m = fmaxf(s0, s1);
    #pragma unroll
    for (int o = 1; o < 16; o <<= 1) m = fmaxf(m, __shfl_xor(m, o));
    float e0 = expf(s0 - m), e1 = expf(s1 - m);
    float sum = e0 + e1;
    #pragma unroll
    for (int o = 1; o < 16; o <<= 1) sum += __shfl_xor(sum, o);
    float inv = 1.0f / sum;
    sc[h][l] = e0 * inv;
    sc[h][l + 16] = e1 * inv;
  }
  __syncthreads();

  {  // PV + elu -> femb[128..256)
    int h = t >> 4, d = t & 15;
    float o = 0.f;
    #pragma unroll 4
    for (int c = 0; c < CTX1; c++)
      o += sc[h][c] * Va[(size_t)idx[c] * 128 + h * 16 + d];
    float e = (o > 0.f) ? o : expm1f(o);
    femb_bf[(size_t)b * 384 + 128 + t] = f2bf(e);
  }
  femb_bf[(size_t)b * 384 + t] = f2bf(emb_gb[(size_t)b * 128 + t]);
  femb_bf[(size_t)b * 384 + 256 + t] = f2bf(simi[(size_t)b * 128 + t]);
}

// ---------------- final projection: result = femb(bf16) @ lin_W + lin_b ----
__global__ __launch_bounds__(64) void final_kernel(
    const short* __restrict__ femb_bf, const short* __restrict__ linWp,
    const float* __restrict__ lin_b, float* __restrict__ outr) {
  const int m0 = blockIdx.x * 16;
  const int lane = threadIdx.x;
  const int fr = lane & 15;
  const int kq = lane >> 4;
  f4 acc[8];
  #pragma unroll
  for (int i = 0; i < 8; i++) acc[i] = (f4){0.f, 0.f, 0.f, 0.f};
  #pragma unroll
  for (int kt = 0; kt < 12; ++kt) {
    bfrag a = *(const bfrag*)&femb_bf[(size_t)(m0 + fr) * 384 + kt * 32 + kq * 8];
    #pragma unroll
    for (int nt = 0; nt < 8; ++nt) {
      bfrag bb = *(const bfrag*)&linWp[(size_t)(kt * 8 + nt) * 512 + lane * 8];
      acc[nt] = __builtin_amdgcn_mfma_f32_16x16x32_bf16(a, bb, acc[nt], 0, 0, 0);
    }
  }
  #pragma unroll
  for (int nt = 0; nt < 8; ++nt) {
    int n = nt * 16 + fr;
    float bv = lin_b[n];
    #pragma unroll
    for (int r = 0; r < 4; ++r)
      outr[(size_t)(m0 + kq * 4 + r) * 128 + n] = acc[nt][r] + bv;
  }
}

// ---------------- loss ----------------
__global__ __launch_bounds__(256) void loss_kernel(
    const float* __restrict__ target, const float* __restrict__ result,
    float* __restrict__ out_loss) {
  int t = threadIdx.x;
  float s = 0.f;
  for (int b = t; b < BSZ; b += 256) {
    float d = target[(size_t)b * 128 + DROPC] - result[(size_t)b * 128 + DROPC];
    s += d * d;
  }
  #pragma unroll
  for (int o = 32; o > 0; o >>= 1) s += __shfl_xor(s, o);
  __shared__ float red[4];
  if ((t & 63) == 0) red[t >> 6] = s;
  __syncthreads();
  if (t == 0) out_loss[0] = (red[0] + red[1] + red[2] + red[3]) * (1.0f / BSZ);
}

extern "C" void kernel_launch(void* const* d_in, const int* in_sizes, int n_in,
                              void* d_out, int out_size, void* d_ws, size_t ws_size,
                              hipStream_t stream) {
  const float* adj = (const float*)d_in[0];
  const float* graphm = (const float*)d_in[1];
  const float* node_emb_gcn = (const float*)d_in[2];
  const float* trainfeature = (const float*)d_in[3];
  const float* target_emb = (const float*)d_in[4];
  const float* bsnf = (const float*)d_in[5];
  const int* batch_node_idx = (const int*)d_in[8];
  const int* node_rd = (const int*)d_in[9];
  const float* translate_W = (const float*)d_in[10];
  const float* translate_b = (const float*)d_in[11];
  const float* paraForCos = (const float*)d_in[12];
  const float* gcn_W = (const float*)d_in[13];
  const float* gcn_b = (const float*)d_in[14];
  const float* gcnE_W = (const float*)d_in[15];
  const float* gcnE_b = (const float*)d_in[16];
  const float* Wq = (const float*)d_in[17];
  const float* Wk = (const float*)d_in[18];
  const float* Wv = (const float*)d_in[19];
  const float* lin_W = (const float*)d_in[20];
  const float* lin_b = (const float*)d_in[21];

  char* ws = (char*)d_ws;
  size_t off = 0;
  auto alloc = [&](size_t bytes) {
    void* p = ws + off;
    off += (bytes + 255) & ~(size_t)255;
    return p;
  };
  short* XgP = (short*)alloc((size_t)128 * NN * 2);
  short* XEP = (short*)alloc((size_t)128 * NN * 2);
  float* tfn = (float*)alloc((size_t)NN * 64 * 4);
  float* wsum = (float*)alloc((size_t)BSZ * 128 * 4);
  float* simi = (float*)alloc((size_t)BSZ * 128 * 4);
  float* Qa = (float*)alloc((size_t)NN * 128 * 4);
  float* Ka = (float*)alloc((size_t)NN * 128 * 4);
  float* Va = (float*)alloc((size_t)NN * 128 * 4);
  float* emb_E = (float*)alloc((size_t)NN * 128 * 4);
  float* emb_gb = (float*)alloc((size_t)BSZ * 128 * 4);
  float* meanpara = (float*)alloc(256);
  short* femb_bf = (short*)alloc((size_t)BSZ * 384 * 2);
  short* linWp = (short*)alloc((size_t)12 * 4096 * 2);

  float* out_res = (float*)d_out;
  float* out_loss = out_res + (size_t)BSZ * 128;

  prep_kernel<<<4109, 256, 0, stream>>>(trainfeature, bsnf, paraForCos, lin_W,
                                        tfn, wsum, meanpara, linWp);
  proj2_kernel<<<dim3(NN / 64, 2), 256, 0, stream>>>(node_emb_gcn, gcn_W, XgP,
                                                     trainfeature, gcnE_W, XEP);
  big_gemm_kernel<<<768, 256, 0, stream>>>(adj, graphm, XgP, XEP, batch_node_idx,
                                           gcnE_b, gcn_b, emb_E, emb_gb);
  qkv_kernel<<<dim3(NN / 64, 3), 256, 0, stream>>>(emb_E, Wq, Wk, Wv, Qa, Ka, Va);
  gemm128_kernel<<<BSZ / 64, 256, 0, stream>>>(wsum, translate_W, translate_b, meanpara,
                                               simi, nullptr);
  attn_kernel<<<BSZ, 128, 0, stream>>>(node_rd, Qa, Ka, Va, tfn, emb_gb, simi, femb_bf);
  final_kernel<<<BSZ / 16, 64, 0, stream>>>(femb_bf, linWp, lin_b, out_res);
  loss_kernel<<<1, 256, 0, stream>>>(target_emb, out_res, out_loss);
}